// Round 4
// baseline (961.489 us; speedup 1.0000x reference)
//
#include <hip/hip_runtime.h>

#define N_VEC   131072
#define D       64
#define KCODES  1024
#define BLK     256
#define VPB     128            // vectors per block (2 threads per vector)
#define HALFK   512            // codes scanned per thread

// ws layout:
// [0, 4096)        int   counts[1024]
// [4096, 4100)     float sse
// [5120, 9216)     float esq[1024]

__device__ __forceinline__ float4 f4fma(float4 a, float4 b, float4 c) {
    return make_float4(fmaf(a.x, b.x, c.x), fmaf(a.y, b.y, c.y),
                       fmaf(a.z, b.z, c.z), fmaf(a.w, b.w, c.w));
}
__device__ __forceinline__ float f4rsum(float4 a) {
    return (a.x + a.y) + (a.z + a.w);
}

__global__ void esq_kernel(const float* __restrict__ cb, float* __restrict__ esq) {
    int k = blockIdx.x * blockDim.x + threadIdx.x;
    if (k < KCODES) {
        const float4* c4 = reinterpret_cast<const float4*>(cb + k * D);
        float4 p = make_float4(0.f, 0.f, 0.f, 0.f);
        #pragma unroll
        for (int i = 0; i < D / 4; ++i) {
            float4 v = c4[i];
            p = f4fma(v, v, p);
        }
        esq[k] = f4rsum(p);
    }
}

__launch_bounds__(BLK, 4)
__global__ void vq_main(const float* __restrict__ z_e, const float* __restrict__ cb,
                        const float* __restrict__ esq,
                        float* __restrict__ zq_out, float* __restrict__ idx_out,
                        float* __restrict__ sse, int* __restrict__ counts) {
    __shared__ float sd[2][VPB];
    __shared__ int   si[2][VPB];
    __shared__ float sred[BLK / 64];

    const int tid = threadIdx.x;
    const int vid = tid & (VPB - 1);
    const int h   = tid >> 7;            // which code-half this thread scans
    const int n   = blockIdx.x * VPB + vid;

    // this thread's z vector in registers (threads t and t+128 duplicate; L1/L2 absorbs)
    float4 z[16];
    const float4* z4 = reinterpret_cast<const float4*>(z_e + (size_t)n * D);
    #pragma unroll
    for (int i = 0; i < 16; ++i) z[i] = z4[i];

    float4 p = make_float4(0.f, 0.f, 0.f, 0.f);
    #pragma unroll
    for (int i = 0; i < 16; ++i) p = f4fma(z[i], z[i], p);
    const float zsq = f4rsum(p);

    float best = INFINITY;
    int   bi = 0;

    // wave-uniform codebook walk: address depends only on loop counter + h
    // (h is wave-uniform since waves are 64 threads) -> compiler emits s_load,
    // codebook streams through the scalar cache, FMAs take SGPR operands.
    const float4* c4 = reinterpret_cast<const float4*>(cb) + (size_t)(h * HALFK) * 16;
    const float*  eq = esq + h * HALFK;
    const int gbase  = h * HALFK;

    #pragma unroll 2
    for (int kk = 0; kk < HALFK; ++kk) {
        float4 s = make_float4(0.f, 0.f, 0.f, 0.f);
        #pragma unroll
        for (int i = 0; i < 16; ++i)
            s = f4fma(z[i], c4[(size_t)kk * 16 + i], s);
        // replicate reference rounding: t1 = fp32(zsq + esq); d = fp32(t1 - 2*dot)
        float t1 = zsq + eq[kk];
        float d  = fmaf(-2.0f, f4rsum(s), t1);
        if (d < best) { best = d; bi = gbase + kk; }   // strict <: lowest index on tie
    }

    // publish per-half results
    sd[h][vid] = best;
    si[h][vid] = bi;
    __syncthreads();

    float v = 0.f;
    if (tid < VPB) {
        float d0 = sd[0][tid], d1 = sd[1][tid];
        int   i0 = si[0][tid], i1 = si[1][tid];
        // half0 holds lower indices: on tie, half0 wins (strict <)
        float db = d0; int ib = i0;
        if (d1 < d0) { db = d1; ib = i1; }
        idx_out[n] = (float)ib;
        atomicAdd(&counts[ib], 1);
        si[0][tid] = ib;                 // for the z_q write phase
        v = db;                          // ||z - z_q||^2 == winning distance
    }
    // block sse reduction
    #pragma unroll
    for (int off = 32; off > 0; off >>= 1) v += __shfl_down(v, off);
    if ((tid & 63) == 0) sred[tid >> 6] = v;
    __syncthreads();
    if (tid == 0) atomicAdd(sse, (sred[0] + sred[1]) + (sred[2] + sred[3]));

    // coalesced z_q write: 128 vectors * 16 float4 = 2048 contiguous float4
    const float4* cb4 = reinterpret_cast<const float4*>(cb);
    float4* zq4 = reinterpret_cast<float4*>(zq_out) + (size_t)blockIdx.x * (VPB * 16);
    #pragma unroll
    for (int i = 0; i < 8; ++i) {
        int m   = i * BLK + tid;         // 0..2047
        int vec = m >> 4;
        int e   = m & 15;
        int cbi = si[0][vec];
        zq4[m] = cb4[(size_t)cbi * 16 + e];
    }
}

__global__ void finalize_kernel(const int* __restrict__ counts, const float* __restrict__ sse,
                                float* __restrict__ out_loss, float* __restrict__ out_perp) {
    __shared__ float red[256];
    int tid = threadIdx.x;
    float hsum = 0.f;
    for (int k = tid; k < KCODES; k += 256) {
        float p = (float)counts[k] / (float)N_VEC;
        hsum += p * logf(p + 1e-12f);
    }
    red[tid] = hsum;
    __syncthreads();
    for (int s = 128; s > 0; s >>= 1) {
        if (tid < s) red[tid] += red[tid + s];
        __syncthreads();
    }
    if (tid == 0) {
        out_loss[0] = 1.25f * sse[0] / 8388608.0f;   // (1+BETA) * mean
        out_perp[0] = expf(-red[0]);
    }
}

extern "C" void kernel_launch(void* const* d_in, const int* in_sizes, int n_in,
                              void* d_out, int out_size, void* d_ws, size_t ws_size,
                              hipStream_t stream) {
    const float* z_e = (const float*)d_in[0];
    const float* cb  = (const float*)d_in[1];

    float* out  = (float*)d_out;
    float* zq   = out;
    float* idxo = out + (size_t)N_VEC * D;          // 8388608
    float* loss = idxo + N_VEC;                     // +131072
    float* perp = loss + 1;

    int*   counts = (int*)d_ws;
    float* sse    = (float*)((char*)d_ws + 4096);
    float* esq    = (float*)((char*)d_ws + 5120);

    hipMemsetAsync(d_ws, 0, 5120, stream);          // zero counts + sse each call
    esq_kernel<<<4, 256, 0, stream>>>(cb, esq);
    vq_main<<<N_VEC / VPB, BLK, 0, stream>>>(z_e, cb, esq, zq, idxo, sse, counts);
    finalize_kernel<<<1, 256, 0, stream>>>(counts, sse, loss, perp);
}

// Round 5
// 504.613 us; speedup vs baseline: 1.9054x; 1.9054x over previous
//
#include <hip/hip_runtime.h>

#define N_VEC   131072
#define D       64
#define KCODES  1024
#define NT      64            // code tiles of 16
#define BLK     256
#define VPB     256           // vectors per block (64 per wave)

typedef __attribute__((ext_vector_type(8))) short bf16x8;
typedef __attribute__((ext_vector_type(4))) float f32x4;

// ws layout:
// [0,4096)        int counts[1024]
// [4096,4100)     float sse
// [5120,9216)     float esq[1024]
// [16384,81920)   float4 efrag[64*64]      (esq in C-row fragment order)
// [81920,344064)  bf16x8 afrag[64*2*2*64]  (codebook hi/lo MFMA A-fragments)

__device__ __forceinline__ float4 f4fma(float4 a, float4 b, float4 c) {
    return make_float4(fmaf(a.x, b.x, c.x), fmaf(a.y, b.y, c.y),
                       fmaf(a.z, b.z, c.z), fmaf(a.w, b.w, c.w));
}
__device__ __forceinline__ float f4rsum(float4 a) {
    return (a.x + a.y) + (a.z + a.w);
}
__device__ __forceinline__ unsigned short f2bf(float f) {
    union { float f; unsigned u; } x; x.f = f;
    unsigned r = x.u + 0x7FFFu + ((x.u >> 16) & 1u);
    return (unsigned short)(r >> 16);
}
__device__ __forceinline__ float bf2f(unsigned short h) {
    union { unsigned u; float f; } x; x.u = ((unsigned)h) << 16;
    return x.f;
}

__global__ void esq_kernel(const float* __restrict__ cb, float* __restrict__ esq) {
    int k = blockIdx.x * blockDim.x + threadIdx.x;
    if (k < KCODES) {
        const float4* c4 = reinterpret_cast<const float4*>(cb + k * D);
        float4 p = make_float4(0.f, 0.f, 0.f, 0.f);
        #pragma unroll
        for (int i = 0; i < 16; ++i) { float4 v = c4[i]; p = f4fma(v, v, p); }
        esq[k] = f4rsum(p);
    }
}

// Build codebook MFMA A-fragments (hi/lo bf16 planes) + esq fragment table.
// A-tile t: rows = codes t*16+(L&15); k-map assumption: k = (L>>4)*8 + e per
// 32-k step (same map used for B in the main kernel -> any HW permutation cancels).
__global__ void frag_kernel(const float* __restrict__ cb, const float* __restrict__ esq,
                            bf16x8* __restrict__ afrag, float4* __restrict__ efrag) {
    const int t = blockIdx.x;        // 0..63
    const int L = threadIdx.x;       // 0..63
    const int r = t * 16 + (L & 15);
    const int g = L >> 4;
    #pragma unroll
    for (int ks = 0; ks < 2; ++ks) {
        const float* src = cb + r * D + ks * 32 + g * 8;
        bf16x8 h, l;
        #pragma unroll
        for (int e = 0; e < 8; ++e) {
            float f = src[e];
            unsigned short hb = f2bf(f);
            float lo = f - bf2f(hb);
            h[e] = (short)hb;
            l[e] = (short)f2bf(lo);
        }
        afrag[((t * 2 + ks) * 2 + 0) * 64 + L] = h;
        afrag[((t * 2 + ks) * 2 + 1) * 64 + L] = l;
    }
    float4 ef;
    ef.x = esq[t * 16 + g * 4 + 0];
    ef.y = esq[t * 16 + g * 4 + 1];
    ef.z = esq[t * 16 + g * 4 + 2];
    ef.w = esq[t * 16 + g * 4 + 3];
    efrag[t * 64 + L] = ef;
}

__device__ __forceinline__ void ins3(float d, int idx,
                                     float& d1, float& d2, float& d3,
                                     int& i1, int& i2, int& i3) {
    if (d < d3) {
        if (d < d1)      { d3 = d2; i3 = i2; d2 = d1; i2 = i1; d1 = d; i1 = idx; }
        else if (d < d2) { d3 = d2; i3 = i2; d2 = d;  i2 = idx; }
        else             { d3 = d;  i3 = idx; }
    }
}

__launch_bounds__(BLK, 2)
__global__ void vq_mfma(const float* __restrict__ z_e, const float* __restrict__ cb,
                        const float* __restrict__ esq,
                        const bf16x8* __restrict__ afrag, const float4* __restrict__ efrag,
                        float* __restrict__ zq_out, float* __restrict__ idx_out,
                        float* __restrict__ sse, int* __restrict__ counts) {
    __shared__ int   scand[VPB][3];
    __shared__ int   swin[VPB];
    __shared__ float sred[BLK / 64];

    const int tid  = threadIdx.x;
    const int wave = tid >> 6;
    const int L    = tid & 63;
    const int lrow = L & 15;
    const int g    = L >> 4;
    const size_t vbase = (size_t)blockIdx.x * VPB + wave * 64;

    // ---- B-fragments: 4 vector-tiles of 16, hi/lo bf16 split, k = g*8+e ----
    bf16x8 zhi[4][2], zlo[4][2];
    #pragma unroll
    for (int b = 0; b < 4; ++b) {
        #pragma unroll
        for (int ks = 0; ks < 2; ++ks) {
            const float* zp = z_e + (vbase + b * 16 + lrow) * D + ks * 32 + g * 8;
            bf16x8 h, l;
            #pragma unroll
            for (int e = 0; e < 8; ++e) {
                float f = zp[e];
                unsigned short hb = f2bf(f);
                float lo = f - bf2f(hb);
                h[e] = (short)hb;
                l[e] = (short)f2bf(lo);
            }
            zhi[b][ks] = h; zlo[b][ks] = l;
        }
    }

    // ---- scan all code tiles, track per-lane top-3 per vector-tile ----
    float d1[4], d2[4], d3[4];
    int   i1[4], i2[4], i3[4];
    #pragma unroll
    for (int b = 0; b < 4; ++b) { d1[b] = d2[b] = d3[b] = INFINITY; i1[b] = i2[b] = i3[b] = 0; }

    for (int t = 0; t < NT; ++t) {
        const bf16x8* ap = afrag + (size_t)t * 256;
        bf16x8 Ah0 = ap[0 * 128 + 0 * 64 + L];
        bf16x8 Al0 = ap[0 * 128 + 1 * 64 + L];
        bf16x8 Ah1 = ap[1 * 128 + 0 * 64 + L];
        bf16x8 Al1 = ap[1 * 128 + 1 * 64 + L];
        float4 ef  = efrag[t * 64 + L];

        f32x4 acc[4];
        #pragma unroll
        for (int b = 0; b < 4; ++b) acc[b] = (f32x4){0.f, 0.f, 0.f, 0.f};

        #pragma unroll
        for (int b = 0; b < 4; ++b) {
            acc[b] = __builtin_amdgcn_mfma_f32_16x16x32_bf16(Ah0, zhi[b][0], acc[b], 0, 0, 0);
            acc[b] = __builtin_amdgcn_mfma_f32_16x16x32_bf16(Ah0, zlo[b][0], acc[b], 0, 0, 0);
            acc[b] = __builtin_amdgcn_mfma_f32_16x16x32_bf16(Al0, zhi[b][0], acc[b], 0, 0, 0);
            acc[b] = __builtin_amdgcn_mfma_f32_16x16x32_bf16(Ah1, zhi[b][1], acc[b], 0, 0, 0);
            acc[b] = __builtin_amdgcn_mfma_f32_16x16x32_bf16(Ah1, zlo[b][1], acc[b], 0, 0, 0);
            acc[b] = __builtin_amdgcn_mfma_f32_16x16x32_bf16(Al1, zhi[b][1], acc[b], 0, 0, 0);
        }

        // epilogue: rank by (esq - 2*dot)  (zsq constant per vector)
        #pragma unroll
        for (int b = 0; b < 4; ++b) {
            #pragma unroll
            for (int j = 0; j < 4; ++j) {
                float ej = (j == 0) ? ef.x : (j == 1) ? ef.y : (j == 2) ? ef.z : ef.w;
                float d  = fmaf(-2.0f, acc[b][j], ej);
                ins3(d, t * 16 + g * 4 + j, d1[b], d2[b], d3[b], i1[b], i2[b], i3[b]);
            }
        }
    }

    // ---- merge top-3 across the 4 lanes sharing each vector column ----
    #pragma unroll
    for (int m = 16; m <= 32; m <<= 1) {
        #pragma unroll
        for (int b = 0; b < 4; ++b) {
            float e1 = __shfl_xor(d1[b], m), e2 = __shfl_xor(d2[b], m), e3 = __shfl_xor(d3[b], m);
            int   j1 = __shfl_xor(i1[b], m), j2 = __shfl_xor(i2[b], m), j3 = __shfl_xor(i3[b], m);
            ins3(e1, j1, d1[b], d2[b], d3[b], i1[b], i2[b], i3[b]);
            ins3(e2, j2, d1[b], d2[b], d3[b], i1[b], i2[b], i3[b]);
            ins3(e3, j3, d1[b], d2[b], d3[b], i1[b], i2[b], i3[b]);
        }
    }
    if (g == 0) {
        #pragma unroll
        for (int b = 0; b < 4; ++b) {
            int lv = wave * 64 + b * 16 + lrow;
            scand[lv][0] = i1[b]; scand[lv][1] = i2[b]; scand[lv][2] = i3[b];
        }
    }
    __syncthreads();

    // ---- exact rescore (bit-replicates R1's reference arithmetic) ----
    const size_t n = (size_t)blockIdx.x * VPB + tid;
    const float4* z4 = reinterpret_cast<const float4*>(z_e + n * D);
    float4 zz[16];
    #pragma unroll
    for (int i = 0; i < 16; ++i) zz[i] = z4[i];
    float4 pq = make_float4(0.f, 0.f, 0.f, 0.f);
    #pragma unroll
    for (int i = 0; i < 16; ++i) pq = f4fma(zz[i], zz[i], pq);
    const float zsq = f4rsum(pq);

    float bd = INFINITY; int bi = 0x7FFFFFFF;
    #pragma unroll
    for (int c = 0; c < 3; ++c) {
        int ci = scand[tid][c];
        const float4* cp = reinterpret_cast<const float4*>(cb + (size_t)ci * D);
        float4 s = make_float4(0.f, 0.f, 0.f, 0.f);
        #pragma unroll
        for (int i = 0; i < 16; ++i) s = f4fma(zz[i], cp[i], s);
        float t1 = zsq + esq[ci];
        float dd = fmaf(-2.0f, f4rsum(s), t1);
        if (dd < bd || (dd == bd && ci < bi)) { bd = dd; bi = ci; }
    }

    idx_out[n] = (float)bi;
    atomicAdd(&counts[bi], 1);
    swin[tid] = bi;

    float v = bd;
    #pragma unroll
    for (int off = 32; off > 0; off >>= 1) v += __shfl_down(v, off);
    if ((tid & 63) == 0) sred[tid >> 6] = v;
    __syncthreads();
    if (tid == 0) atomicAdd(sse, (sred[0] + sred[1]) + (sred[2] + sred[3]));

    // ---- coalesced z_q write ----
    const float4* cb4 = reinterpret_cast<const float4*>(cb);
    float4* zq4 = reinterpret_cast<float4*>(zq_out) + (size_t)blockIdx.x * (VPB * 16);
    #pragma unroll
    for (int i = 0; i < 16; ++i) {
        int mi  = i * BLK + tid;       // 0..4095
        int vec = mi >> 4;
        int e   = mi & 15;
        zq4[mi] = cb4[(size_t)swin[vec] * 16 + e];
    }
}

__global__ void finalize_kernel(const int* __restrict__ counts, const float* __restrict__ sse,
                                float* __restrict__ out_loss, float* __restrict__ out_perp) {
    __shared__ float red[256];
    int tid = threadIdx.x;
    float hsum = 0.f;
    for (int k = tid; k < KCODES; k += 256) {
        float p = (float)counts[k] / (float)N_VEC;
        hsum += p * logf(p + 1e-12f);
    }
    red[tid] = hsum;
    __syncthreads();
    for (int s = 128; s > 0; s >>= 1) {
        if (tid < s) red[tid] += red[tid + s];
        __syncthreads();
    }
    if (tid == 0) {
        out_loss[0] = 1.25f * sse[0] / 8388608.0f;   // (1+BETA) * mean
        out_perp[0] = expf(-red[0]);
    }
}

extern "C" void kernel_launch(void* const* d_in, const int* in_sizes, int n_in,
                              void* d_out, int out_size, void* d_ws, size_t ws_size,
                              hipStream_t stream) {
    const float* z_e = (const float*)d_in[0];
    const float* cb  = (const float*)d_in[1];

    float* out  = (float*)d_out;
    float* zq   = out;
    float* idxo = out + (size_t)N_VEC * D;          // 8388608
    float* loss = idxo + N_VEC;                     // +131072
    float* perp = loss + 1;

    char* ws = (char*)d_ws;
    int*    counts = (int*)ws;
    float*  sse    = (float*)(ws + 4096);
    float*  esq    = (float*)(ws + 5120);
    float4* efrag  = (float4*)(ws + 16384);
    bf16x8* afrag  = (bf16x8*)(ws + 81920);

    hipMemsetAsync(d_ws, 0, 5120, stream);          // zero counts + sse each call
    esq_kernel<<<4, 256, 0, stream>>>(cb, esq);
    frag_kernel<<<NT, 64, 0, stream>>>(cb, esq, afrag, efrag);
    vq_mfma<<<N_VEC / VPB, BLK, 0, stream>>>(z_e, cb, esq, afrag, efrag, zq, idxo, sse, counts);
    finalize_kernel<<<1, 256, 0, stream>>>(counts, sse, loss, perp);
}

// Round 6
// 152.295 us; speedup vs baseline: 6.3133x; 3.3134x over previous
//
#include <hip/hip_runtime.h>

#define N_VEC   131072
#define D       64
#define KCODES  1024
#define NT      64            // code tiles of 16
#define BLK     256
#define VPB     128           // vectors per block (32 per wave: 2 b-tiles)
#define CH      4             // code tiles staged per LDS chunk

typedef __attribute__((ext_vector_type(8))) short bf16x8;
typedef __attribute__((ext_vector_type(4))) float f32x4;

// ws layout:
// [0,4096)        int counts[1024]
// [4096,4100)     float sse
// [5120,9216)     float esq[1024]
// [16384,81920)   float4 efrag[64*64]      (esq in C-row fragment order)
// [81920,344064)  bf16x8 afrag[64*4*64]    (codebook hi/lo MFMA A-fragments)

__device__ __forceinline__ float4 f4fma(float4 a, float4 b, float4 c) {
    return make_float4(fmaf(a.x, b.x, c.x), fmaf(a.y, b.y, c.y),
                       fmaf(a.z, b.z, c.z), fmaf(a.w, b.w, c.w));
}
__device__ __forceinline__ float f4rsum(float4 a) {
    return (a.x + a.y) + (a.z + a.w);
}
__device__ __forceinline__ unsigned short f2bf(float f) {
    union { float f; unsigned u; } x; x.f = f;
    unsigned r = x.u + 0x7FFFu + ((x.u >> 16) & 1u);
    return (unsigned short)(r >> 16);
}
__device__ __forceinline__ float bf2f(unsigned short h) {
    union { unsigned u; float f; } x; x.u = ((unsigned)h) << 16;
    return x.f;
}

__global__ void esq_kernel(const float* __restrict__ cb, float* __restrict__ esq) {
    int k = blockIdx.x * blockDim.x + threadIdx.x;
    if (k < KCODES) {
        const float4* c4 = reinterpret_cast<const float4*>(cb + k * D);
        float4 p = make_float4(0.f, 0.f, 0.f, 0.f);
        #pragma unroll
        for (int i = 0; i < 16; ++i) { float4 v = c4[i]; p = f4fma(v, v, p); }
        esq[k] = f4rsum(p);
    }
}

// Build codebook MFMA A-fragments (hi/lo bf16 planes) + esq fragment table.
// Tile t fragment f = ks*2+plane at afrag[(t*4+f)*64 + L]; rows = t*16+(L&15),
// k-map: k = (L>>4)*8 + e per 32-k step (same map used for B -> permutation cancels).
__global__ void frag_kernel(const float* __restrict__ cb, const float* __restrict__ esq,
                            bf16x8* __restrict__ afrag, float4* __restrict__ efrag) {
    const int t = blockIdx.x;        // 0..63
    const int L = threadIdx.x;       // 0..63
    const int r = t * 16 + (L & 15);
    const int g = L >> 4;
    #pragma unroll
    for (int ks = 0; ks < 2; ++ks) {
        const float* src = cb + r * D + ks * 32 + g * 8;
        bf16x8 h, l;
        #pragma unroll
        for (int e = 0; e < 8; ++e) {
            float f = src[e];
            unsigned short hb = f2bf(f);
            float lo = f - bf2f(hb);
            h[e] = (short)hb;
            l[e] = (short)f2bf(lo);
        }
        afrag[(t * 4 + ks * 2 + 0) * 64 + L] = h;
        afrag[(t * 4 + ks * 2 + 1) * 64 + L] = l;
    }
    float4 ef;
    ef.x = esq[t * 16 + g * 4 + 0];
    ef.y = esq[t * 16 + g * 4 + 1];
    ef.z = esq[t * 16 + g * 4 + 2];
    ef.w = esq[t * 16 + g * 4 + 3];
    efrag[t * 64 + L] = ef;
}

// branchless sorted-top3 insert (strict <: earliest-scanned wins ties)
__device__ __forceinline__ void ins3(float d, int idx,
                                     float& d1, float& d2, float& d3,
                                     int& i1, int& i2, int& i3) {
    bool b1 = d < d1, b2 = d < d2, b3 = d < d3;
    float nd3 = b2 ? d2 : (b3 ? d : d3);
    int   ni3 = b2 ? i2 : (b3 ? idx : i3);
    float nd2 = b1 ? d1 : (b2 ? d : d2);
    int   ni2 = b1 ? i1 : (b2 ? idx : i2);
    d1 = b1 ? d : d1;
    i1 = b1 ? idx : i1;
    d2 = nd2; i2 = ni2; d3 = nd3; i3 = ni3;
}

__launch_bounds__(BLK, 4)
__global__ void vq_mfma(const float* __restrict__ z_e, const float* __restrict__ cb,
                        const float* __restrict__ esq,
                        const float4* __restrict__ afrag4, const float4* __restrict__ efrag,
                        float* __restrict__ zq_out, float* __restrict__ idx_out,
                        float* __restrict__ sse, int* __restrict__ counts) {
    __shared__ float4 scb[CH * 4 * 64];   // 16 KB: CH tiles of A-fragments
    __shared__ float4 sef[CH * 64];       // 4 KB: esq fragments
    __shared__ float  sbd[2][VPB];
    __shared__ int    sbi[2][VPB];
    __shared__ int    scand[VPB][3];
    __shared__ int    swin[VPB];
    __shared__ float  sred[BLK / 64];

    const int tid  = threadIdx.x;
    const int wave = tid >> 6;
    const int L    = tid & 63;
    const int lrow = L & 15;
    const int g    = L >> 4;
    const size_t vbase = (size_t)blockIdx.x * VPB + wave * 32;

    // ---- B-fragments: 2 vector-tiles of 16, hi/lo bf16 split, k = g*8+e ----
    bf16x8 zhi[2][2], zlo[2][2];
    #pragma unroll
    for (int b = 0; b < 2; ++b) {
        #pragma unroll
        for (int ks = 0; ks < 2; ++ks) {
            const float* zp = z_e + (vbase + b * 16 + lrow) * D + ks * 32 + g * 8;
            float4 u0 = *reinterpret_cast<const float4*>(zp);
            float4 u1 = *reinterpret_cast<const float4*>(zp + 4);
            float fv[8] = {u0.x, u0.y, u0.z, u0.w, u1.x, u1.y, u1.z, u1.w};
            bf16x8 h, l;
            #pragma unroll
            for (int e = 0; e < 8; ++e) {
                unsigned short hb = f2bf(fv[e]);
                float lo = fv[e] - bf2f(hb);
                h[e] = (short)hb;
                l[e] = (short)f2bf(lo);
            }
            zhi[b][ks] = h; zlo[b][ks] = l;
        }
    }

    float d1[2], d2[2], d3[2];
    int   i1[2], i2[2], i3[2];
    #pragma unroll
    for (int b = 0; b < 2; ++b) { d1[b] = d2[b] = d3[b] = INFINITY; i1[b] = i2[b] = i3[b] = 0; }

    // ---- chunked LDS-staged scan over 64 code tiles ----
    for (int c = 0; c < NT / CH; ++c) {
        // issue chunk loads early (latency overlaps previous chunk's compute)
        float4 stg[5];
        const float4* gA = afrag4 + (size_t)c * (CH * 4 * 64);
        const float4* gE = efrag + (size_t)c * (CH * 64);
        #pragma unroll
        for (int i = 0; i < 4; ++i) stg[i] = gA[i * BLK + tid];
        stg[4] = gE[tid];
        __syncthreads();               // all waves done reading previous chunk
        #pragma unroll
        for (int i = 0; i < 4; ++i) scb[i * BLK + tid] = stg[i];
        sef[tid] = stg[4];
        __syncthreads();               // chunk ready

        #pragma unroll
        for (int tt = 0; tt < CH; ++tt) {
            const int t = c * CH + tt;
            const bf16x8* fr = reinterpret_cast<const bf16x8*>(scb + tt * 256);
            bf16x8 Ah0 = fr[0 * 64 + L];
            bf16x8 Al0 = fr[1 * 64 + L];
            bf16x8 Ah1 = fr[2 * 64 + L];
            bf16x8 Al1 = fr[3 * 64 + L];
            float4 ef  = sef[tt * 64 + L];

            f32x4 acc[2];
            #pragma unroll
            for (int b = 0; b < 2; ++b) {
                acc[b] = (f32x4){0.f, 0.f, 0.f, 0.f};
                acc[b] = __builtin_amdgcn_mfma_f32_16x16x32_bf16(Ah0, zhi[b][0], acc[b], 0, 0, 0);
                acc[b] = __builtin_amdgcn_mfma_f32_16x16x32_bf16(Ah0, zlo[b][0], acc[b], 0, 0, 0);
                acc[b] = __builtin_amdgcn_mfma_f32_16x16x32_bf16(Al0, zhi[b][0], acc[b], 0, 0, 0);
                acc[b] = __builtin_amdgcn_mfma_f32_16x16x32_bf16(Ah1, zhi[b][1], acc[b], 0, 0, 0);
                acc[b] = __builtin_amdgcn_mfma_f32_16x16x32_bf16(Ah1, zlo[b][1], acc[b], 0, 0, 0);
                acc[b] = __builtin_amdgcn_mfma_f32_16x16x32_bf16(Al1, zhi[b][1], acc[b], 0, 0, 0);
            }

            #pragma unroll
            for (int b = 0; b < 2; ++b) {
                #pragma unroll
                for (int j = 0; j < 4; ++j) {
                    float ej = (j == 0) ? ef.x : (j == 1) ? ef.y : (j == 2) ? ef.z : ef.w;
                    float d  = fmaf(-2.0f, acc[b][j], ej);
                    ins3(d, t * 16 + g * 4 + j, d1[b], d2[b], d3[b], i1[b], i2[b], i3[b]);
                }
            }
        }
    }

    // ---- merge top-3 across the 4 lanes sharing each vector column ----
    #pragma unroll
    for (int m = 16; m <= 32; m <<= 1) {
        #pragma unroll
        for (int b = 0; b < 2; ++b) {
            float e1 = __shfl_xor(d1[b], m), e2 = __shfl_xor(d2[b], m), e3 = __shfl_xor(d3[b], m);
            int   j1 = __shfl_xor(i1[b], m), j2 = __shfl_xor(i2[b], m), j3 = __shfl_xor(i3[b], m);
            ins3(e1, j1, d1[b], d2[b], d3[b], i1[b], i2[b], i3[b]);
            ins3(e2, j2, d1[b], d2[b], d3[b], i1[b], i2[b], i3[b]);
            ins3(e3, j3, d1[b], d2[b], d3[b], i1[b], i2[b], i3[b]);
        }
    }
    if (g == 0) {
        #pragma unroll
        for (int b = 0; b < 2; ++b) {
            int lv = wave * 32 + b * 16 + lrow;
            scand[lv][0] = i1[b]; scand[lv][1] = i2[b]; scand[lv][2] = i3[b];
        }
    }
    __syncthreads();

    // ---- exact rescore, split across thread halves (bit-replicates reference) ----
    const int vid = tid & (VPB - 1);
    const int hh  = tid >> 7;
    const size_t n = (size_t)blockIdx.x * VPB + vid;
    const float4* z4 = reinterpret_cast<const float4*>(z_e + n * D);
    float4 zz[16];
    #pragma unroll
    for (int i = 0; i < 16; ++i) zz[i] = z4[i];
    float4 pq = make_float4(0.f, 0.f, 0.f, 0.f);
    #pragma unroll
    for (int i = 0; i < 16; ++i) pq = f4fma(zz[i], zz[i], pq);
    const float zsq = f4rsum(pq);

    float bd = INFINITY; int bi = 0x7FFFFFFF;
    const int c0 = hh ? 2 : 0;
    const int c1 = hh ? 2 : 1;       // half 0: cands 0,1; half 1: cand 2
    #pragma unroll
    for (int c = 0; c < 2; ++c) {
        int ci = scand[vid][(c == 0) ? c0 : c1];
        const float4* cp = reinterpret_cast<const float4*>(cb + (size_t)ci * D);
        float4 s = make_float4(0.f, 0.f, 0.f, 0.f);
        #pragma unroll
        for (int i = 0; i < 16; ++i) s = f4fma(zz[i], cp[i], s);
        float t1 = zsq + esq[ci];
        float dd = fmaf(-2.0f, f4rsum(s), t1);
        if (dd < bd || (dd == bd && ci < bi)) { bd = dd; bi = ci; }
    }
    sbd[hh][vid] = bd; sbi[hh][vid] = bi;
    __syncthreads();

    float v = 0.f;
    if (tid < VPB) {
        float da = sbd[0][tid], db = sbd[1][tid];
        int   ia = sbi[0][tid], ib = sbi[1][tid];
        float bdv = da; int biv = ia;
        if (db < da || (db == da && ib < ia)) { bdv = db; biv = ib; }
        idx_out[n] = (float)biv;
        atomicAdd(&counts[biv], 1);
        swin[tid] = biv;
        v = bdv;                      // ||z - z_q||^2 == winning exact distance
    }
    #pragma unroll
    for (int off = 32; off > 0; off >>= 1) v += __shfl_down(v, off);
    if ((tid & 63) == 0) sred[tid >> 6] = v;
    __syncthreads();
    if (tid == 0) atomicAdd(sse, (sred[0] + sred[1]) + (sred[2] + sred[3]));

    // ---- coalesced z_q write: 128 vectors * 16 float4 ----
    const float4* cb4 = reinterpret_cast<const float4*>(cb);
    float4* zq4 = reinterpret_cast<float4*>(zq_out) + (size_t)blockIdx.x * (VPB * 16);
    #pragma unroll
    for (int i = 0; i < 8; ++i) {
        int mi  = i * BLK + tid;      // 0..2047
        int vec = mi >> 4;
        int e   = mi & 15;
        zq4[mi] = cb4[(size_t)swin[vec] * 16 + e];
    }
}

__global__ void finalize_kernel(const int* __restrict__ counts, const float* __restrict__ sse,
                                float* __restrict__ out_loss, float* __restrict__ out_perp) {
    __shared__ float red[256];
    int tid = threadIdx.x;
    float hsum = 0.f;
    for (int k = tid; k < KCODES; k += 256) {
        float p = (float)counts[k] / (float)N_VEC;
        hsum += p * logf(p + 1e-12f);
    }
    red[tid] = hsum;
    __syncthreads();
    for (int s = 128; s > 0; s >>= 1) {
        if (tid < s) red[tid] += red[tid + s];
        __syncthreads();
    }
    if (tid == 0) {
        out_loss[0] = 1.25f * sse[0] / 8388608.0f;   // (1+BETA) * mean
        out_perp[0] = expf(-red[0]);
    }
}

extern "C" void kernel_launch(void* const* d_in, const int* in_sizes, int n_in,
                              void* d_out, int out_size, void* d_ws, size_t ws_size,
                              hipStream_t stream) {
    const float* z_e = (const float*)d_in[0];
    const float* cb  = (const float*)d_in[1];

    float* out  = (float*)d_out;
    float* zq   = out;
    float* idxo = out + (size_t)N_VEC * D;          // 8388608
    float* loss = idxo + N_VEC;                     // +131072
    float* perp = loss + 1;

    char* ws = (char*)d_ws;
    int*    counts = (int*)ws;
    float*  sse    = (float*)(ws + 4096);
    float*  esq    = (float*)(ws + 5120);
    float4* efrag  = (float4*)(ws + 16384);
    bf16x8* afrag  = (bf16x8*)(ws + 81920);

    hipMemsetAsync(d_ws, 0, 5120, stream);          // zero counts + sse each call
    esq_kernel<<<4, 256, 0, stream>>>(cb, esq);
    frag_kernel<<<NT, 64, 0, stream>>>(cb, esq, afrag, efrag);
    vq_mfma<<<N_VEC / VPB, BLK, 0, stream>>>(z_e, cb, esq, (const float4*)afrag, efrag,
                                             zq, idxo, sse, counts);
    finalize_kernel<<<1, 256, 0, stream>>>(counts, sse, loss, perp);
}